// Round 10
// baseline (411.056 us; speedup 1.0000x reference)
//
#include <hip/hip_runtime.h>
#include <hip/hip_bf16.h>

typedef __attribute__((ext_vector_type(8))) short short8;
typedef __attribute__((ext_vector_type(4))) float f32x4;
using bf16 = __hip_bfloat16;

__device__ __forceinline__ unsigned short f2bf(float f) {
    unsigned u = __float_as_uint(f);
    u += 0x7fff + ((u >> 16) & 1);           // round-to-nearest-even
    return (unsigned short)(u >> 16);
}
__device__ __forceinline__ float bf2f(unsigned short s) {
    return __uint_as_float(((unsigned)s) << 16);
}
// async global->LDS DMA, 16B/lane; global lane addrs CONTIGUOUS (packed layout)
__device__ __forceinline__ void gl_lds16(const unsigned short* g, unsigned short* l) {
    __builtin_amdgcn_global_load_lds(
        (const __attribute__((address_space(1))) unsigned int*)g,
        (__attribute__((address_space(3))) unsigned int*)l, 16, 0, 0);
}
// device-scope atomics for cross-block producer/consumer sync
__device__ __forceinline__ int aload(const int* p) {
    return __hip_atomic_load(p, __ATOMIC_ACQUIRE, __HIP_MEMORY_SCOPE_AGENT);
}
__device__ __forceinline__ void astore(int* p, int v) {
    __hip_atomic_store(p, v, __ATOMIC_RELEASE, __HIP_MEMORY_SCOPE_AGENT);
}
__device__ __forceinline__ void aadd(int* p, int v) {
    __hip_atomic_fetch_add(p, v, __ATOMIC_RELEASE, __HIP_MEMORY_SCOPE_AGENT);
}

// Packed layout (shorts): off = ((g*64 + s)*64 + r)*8   g=row/64, s=k/8, r=row%64
// => a wave staging (g, s, rows 0..63) reads 64 lanes x 16B = 1KB contiguous.

// ---------------------------------------------------------------- pack fp32 -> packed bf16 (+ zero ssq & flags)
__global__ __launch_bounds__(256) void pack_kernel(
    const float* __restrict__ X, const float* __restrict__ Wq, const float* __restrict__ Wk,
    const float* __restrict__ Wv, const float* __restrict__ Wo,
    bf16* __restrict__ Xp, bf16* __restrict__ Wqp, bf16* __restrict__ Wkp,
    bf16* __restrict__ Wvp, bf16* __restrict__ Wop, float* __restrict__ ssq,
    int* __restrict__ flg)
{
    __shared__ __align__(16) unsigned short sm[4096];   // [s_local 8][r 64][8]
    int id = blockIdx.x;
    int tid = threadIdx.x;
    if (id < 8) {
        int zi = id * 1024 + tid * 4;
        *(float4*)&ssq[zi] = make_float4(0.f, 0.f, 0.f, 0.f);
    } else if (id == 8) {
        *(int4*)&flg[tid * 4] = make_int4(0, 0, 0, 0);   // 1024 ints: ScT flags + done counters
    }
    const float* src; unsigned short* dst; int g, sc;
    if (id < 512) { src = X; dst = (unsigned short*)Xp; g = id >> 3; sc = id & 7; }
    else {
        int t = id - 512; int wsel = t >> 6; int u = t & 63;
        g = u >> 3; sc = u & 7;
        src = (wsel == 0) ? Wq : ((wsel == 1) ? Wk : ((wsel == 2) ? Wv : Wo));
        dst = (unsigned short*)((wsel == 0) ? Wqp : ((wsel == 1) ? Wkp : ((wsel == 2) ? Wvp : Wop)));
    }
    int r = tid >> 2, kq = tid & 3;          // 64 rows x 4 k-chunks of 16
    const float* sp = src + (size_t)(g * 64 + r) * 512 + sc * 64 + kq * 16;
    #pragma unroll
    for (int i = 0; i < 4; ++i) {
        float4 v = *(const float4*)(sp + i * 4);
        int kk = kq * 16 + i * 4;            // local k 0..63
        int sl = kk >> 3, el = kk & 7;       // el in {0,4}
        ushort4 u4;
        u4.x = f2bf(v.x); u4.y = f2bf(v.y); u4.z = f2bf(v.z); u4.w = f2bf(v.w);
        *(ushort4*)&sm[(sl * 64 + r) * 8 + el] = u4;
    }
    __syncthreads();
    unsigned short* dp = dst + (size_t)g * 32768 + sc * 4096;   // 8 s-values contiguous
    *(uint4*)(dp + tid * 16)     = *(const uint4*)&sm[tid * 16];
    *(uint4*)(dp + tid * 16 + 8) = *(const uint4*)&sm[tid * 16 + 8];
}

// ---------------------------------------------------------------- QKV GEMM (packed bf16 in, bf16 out + sumsq)
// Out(z) = act(x @ W(z)^T + b(z)) bf16; z<2 accumulates per-row sumsq (post-relu) into ssq[z*4096+row].
// Tile 64x128; staging = pure global_load_lds_dwordx4 (3/wave/k-iter).  Grid (64,4,3) = 768 blocks.
__global__ __launch_bounds__(256) void qkv_gemm_kernel(
    const bf16* __restrict__ Xp,
    const bf16* __restrict__ W0p, const bf16* __restrict__ W1p, const bf16* __restrict__ W2p,
    const float* __restrict__ b0, const float* __restrict__ b1, const float* __restrict__ b2,
    bf16* __restrict__ O0, bf16* __restrict__ O1, bf16* __restrict__ O2,
    float* __restrict__ ssq)
{
    __shared__ __align__(16) unsigned short smem[8192];   // As[4][64][8] 2048 + Bs[4][128][8] 4096; epilogue C 64x128
    unsigned short* As = smem;
    unsigned short* Bs = smem + 2048;
    int z = blockIdx.z;
    const unsigned short* Wg = (const unsigned short*)((z == 0) ? W0p : ((z == 1) ? W1p : W2p));
    const float* bias = (z == 0) ? b0 : ((z == 1) ? b1 : b2);
    unsigned short* Out = (unsigned short*)((z == 0) ? O0 : ((z == 1) ? O1 : O2));
    const unsigned short* Ag = (const unsigned short*)Xp;

    int g  = blockIdx.x;              // m-group (64 rows)
    int gB = blockIdx.y * 2;          // two 64-row W groups = 128 n
    int m0 = g * 64;
    int n0 = blockIdx.y * 128;
    int tid = threadIdx.x;
    int lane = tid & 63;
    int w = tid >> 6;
    int wm = (w >> 1) * 32;
    int wn = (w & 1) * 64;
    int fr = lane & 15, qf = lane >> 4;

    f32x4 zero4 = {0.f, 0.f, 0.f, 0.f};
    f32x4 acc[2][4];
    #pragma unroll
    for (int t = 0; t < 2; ++t)
        #pragma unroll
        for (int u = 0; u < 4; ++u) acc[t][u] = zero4;

    for (int kw = 0; kw < 16; ++kw) {
        int s0 = kw * 4;
        __syncthreads();
        gl_lds16(Ag + ((size_t)(g * 64 + s0 + w) * 64 + lane) * 8, As + w * 512);
        gl_lds16(Wg + ((size_t)(gB * 64 + s0 + w) * 64 + lane) * 8, Bs + w * 1024);
        gl_lds16(Wg + ((size_t)((gB + 1) * 64 + s0 + w) * 64 + lane) * 8, Bs + w * 1024 + 512);
        __syncthreads();
        short8 af[2], bfr[4];
        #pragma unroll
        for (int t = 0; t < 2; ++t) af[t] = *(const short8*)&As[(qf * 64 + wm + t * 16 + fr) * 8];
        #pragma unroll
        for (int u = 0; u < 4; ++u) bfr[u] = *(const short8*)&Bs[(qf * 128 + wn + u * 16 + fr) * 8];
        #pragma unroll
        for (int t = 0; t < 2; ++t)
            #pragma unroll
            for (int u = 0; u < 4; ++u)
                acc[t][u] = __builtin_amdgcn_mfma_f32_16x16x32_bf16(af[t], bfr[u], acc[t][u], 0, 0, 0);
    }

    bool relu = (z < 2);
    int rb = qf * 4;
    #pragma unroll
    for (int t = 0; t < 2; ++t)
        #pragma unroll
        for (int u = 0; u < 4; ++u) {
            float bv = bias[n0 + wn + u * 16 + fr];
            #pragma unroll
            for (int r = 0; r < 4; ++r) {
                float v = acc[t][u][r] + bv;
                if (relu) v = fmaxf(v, 0.f);
                acc[t][u][r] = v;
            }
        }
    if (relu) {
        #pragma unroll
        for (int t = 0; t < 2; ++t)
            #pragma unroll
            for (int r = 0; r < 4; ++r) {
                float s = 0.f;
                #pragma unroll
                for (int u = 0; u < 4; ++u) s += acc[t][u][r] * acc[t][u][r];
                #pragma unroll
                for (int off = 1; off < 16; off <<= 1) s += __shfl_xor(s, off, 64);
                if (fr == 0) atomicAdd(&ssq[z * 4096 + m0 + wm + t * 16 + rb + r], s);
            }
    }
    __syncthreads();                       // LDS dead -> C staging [row][128]
    #pragma unroll
    for (int t = 0; t < 2; ++t)
        #pragma unroll
        for (int u = 0; u < 4; ++u)
            #pragma unroll
            for (int r = 0; r < 4; ++r)
                smem[(wm + t * 16 + rb + r) * 128 + wn + u * 16 + fr] = f2bf(acc[t][u][r]);
    __syncthreads();
    #pragma unroll
    for (int rep = 0; rep < 4; ++rep) {
        int idx8 = rep * 256 + tid;
        int row = idx8 >> 4, col8 = (idx8 & 15) * 8;
        *(uint4*)(Out + (size_t)(m0 + row) * 512 + n0 + col8) = *(const uint4*)&smem[row * 128 + col8];
    }
}

// ---------------------------------------------------------------- fused tail: chunk_kv -> plane-prefix -> attn -> oproj
// One 512-block dispatch (2 blocks/CU, all co-resident). Cross-block deps via device-scope
// release/acquire flags: flg[0..511] = ScT plane ready; flg[512+c] = #heads done with attn chunk c.
__global__ __launch_bounds__(256) void tail_kernel(
    const bf16* __restrict__ Qb, const bf16* __restrict__ Kb, const bf16* __restrict__ Vb,
    bf16* __restrict__ Vt_g, bf16* __restrict__ AOb,
    float* __restrict__ ScT, const float* __restrict__ ssq, int* __restrict__ flg,
    const bf16* __restrict__ Wop, const float* __restrict__ bo, float* __restrict__ out)
{
    __shared__ __align__(16) unsigned char SMraw[43008];   // 42 KB union
    int blk = blockIdx.x;
    int tid = threadIdx.x;
    int lane = tid & 63;
    int w = tid >> 6;
    int fr = lane & 15, q = lane >> 4;
    f32x4 zero4 = {0.f, 0.f, 0.f, 0.f};
    int n = blk >> 5, c = blk & 31;
    int b = n >> 3, h = n & 7;

    // ---------- Phase A: chunk (64-row) KV sums + scaled V^T ----------
    {
        float* Ksf = (float*)SMraw;            // 64x64 f32
        float* Vsf = Ksf + 4096;
        const unsigned short* Kg = (const unsigned short*)Kb;
        const unsigned short* Vg = (const unsigned short*)Vb;
        int td = tid >> 4, tm = tid & 15;
        int d0 = td * 4, m0 = tm * 4;
        #pragma unroll
        for (int rep = 0; rep < 4; ++rep) {
            int idx = rep * 1024 + tid * 4;
            int j = idx >> 6, d = idx & 63;
            int grow = (c * 64 + j) * 2 + b;
            ushort4 ku = *(const ushort4*)&Kg[(size_t)grow * 512 + h * 64 + d];
            ushort4 vu = *(const ushort4*)&Vg[(size_t)grow * 512 + h * 64 + d];
            float rk = 1.f / fmaxf(sqrtf(ssq[4096 + grow]), 1e-12f);
            *(float4*)&Ksf[j * 64 + d] = make_float4(bf2f(ku.x), bf2f(ku.y), bf2f(ku.z), bf2f(ku.w));
            *(float4*)&Vsf[j * 64 + d] = make_float4(bf2f(vu.x) * rk, bf2f(vu.y) * rk,
                                                     bf2f(vu.z) * rk, bf2f(vu.w) * rk);
        }
        __syncthreads();
        float acc[4][4] = {};
        for (int j = 0; j < 64; ++j) {
            float4 kv = *(const float4*)&Ksf[j * 64 + d0];
            float4 vv = *(const float4*)&Vsf[j * 64 + m0];
            acc[0][0] += kv.x*vv.x; acc[0][1] += kv.x*vv.y; acc[0][2] += kv.x*vv.z; acc[0][3] += kv.x*vv.w;
            acc[1][0] += kv.y*vv.x; acc[1][1] += kv.y*vv.y; acc[1][2] += kv.y*vv.z; acc[1][3] += kv.y*vv.w;
            acc[2][0] += kv.z*vv.x; acc[2][1] += kv.z*vv.y; acc[2][2] += kv.z*vv.z; acc[2][3] += kv.z*vv.w;
            acc[3][0] += kv.w*vv.x; acc[3][1] += kv.w*vv.y; acc[3][2] += kv.w*vv.z; acc[3][3] += kv.w*vv.w;
        }
        int vm = tid & 63, vj0 = (tid >> 6) * 16;
        unsigned short tmp[16];
        #pragma unroll
        for (int i = 0; i < 16; ++i) tmp[i] = f2bf(Vsf[(vj0 + i) * 64 + vm]);
        size_t vtoff = (size_t)n * 131072 + (size_t)vm * 2048 + c * 64 + vj0;
        *(uint4*)((unsigned short*)Vt_g + vtoff)     = *(uint4*)&tmp[0];
        *(uint4*)((unsigned short*)Vt_g + vtoff + 8) = *(uint4*)&tmp[8];

        float* outp = ScT + (size_t)blk * 4096;
        #pragma unroll
        for (int j2 = 0; j2 < 4; ++j2) {
            float4 o4 = make_float4(acc[0][j2], acc[1][j2], acc[2][j2], acc[3][j2]);
            *(float4*)&outp[(m0 + j2) * 64 + d0] = o4;
        }
        __threadfence();                       // make plane + Vt visible device-wide
        __syncthreads();
        if (tid == 0) astore(&flg[blk], 1);    // release: plane (n,c) ready
    }

    // ---------- Phase B: exclusive prefix of ScT planes -> Sps (LDS bf16, [m][d] stride 72) ----------
    unsigned short* Sps = (unsigned short*)SMraw;            // 64*72 shorts (9216 B)
    {
        if (c > 0 && tid < c)
            while (aload(&flg[n * 32 + tid]) == 0) __builtin_amdgcn_s_sleep(1);
        __syncthreads();
        __threadfence();                       // acquire side for all threads
        const float* scb = ScT + (size_t)(n * 32) * 4096;
        float4 a4[4];
        #pragma unroll
        for (int s = 0; s < 4; ++s) a4[s] = make_float4(0.f, 0.f, 0.f, 0.f);
        for (int cp = 0; cp < c; ++cp) {
            #pragma unroll
            for (int s = 0; s < 4; ++s) {
                float4 v = *(const float4*)&scb[(size_t)cp * 4096 + s * 1024 + tid * 4];
                a4[s].x += v.x; a4[s].y += v.y; a4[s].z += v.z; a4[s].w += v.w;
            }
        }
        __syncthreads();                       // phase A LDS dead
        #pragma unroll
        for (int s = 0; s < 4; ++s) {
            int E = s * 1024 + tid * 4;
            int m = E >> 6, d = E & 63;
            ushort4 u4;
            u4.x = f2bf(a4[s].x); u4.y = f2bf(a4[s].y); u4.z = f2bf(a4[s].z); u4.w = f2bf(a4[s].w);
            *(ushort4*)&Sps[m * 72 + d] = u4;
        }
    }

    // ---------- Phase C: MFMA causal linear attention for (head n, 64-chunk c) ----------
    {
        unsigned short* Qs = (unsigned short*)(SMraw + 9216);    // 64x72
        unsigned short* Ks = (unsigned short*)(SMraw + 18432);   // 64x72
        unsigned short* Vt = (unsigned short*)(SMraw + 27648);   // 64x72
        unsigned short* Ps = (unsigned short*)(SMraw + 36864);   // 4x16x40
        const unsigned short* Qg = (const unsigned short*)Qb;
        const unsigned short* Kg = (const unsigned short*)Kb;
        const unsigned short* Vg = (const unsigned short*)Vt_g;

        #pragma unroll
        for (int rep = 0; rep < 2; ++rep) {
            int idx = rep * 256 + tid;
            int l = idx >> 3, dc = (idx & 7) * 8;
            size_t goff = (size_t)((c * 64 + l) * 2 + b) * 512 + h * 64 + dc;
            *(uint4*)&Qs[l * 72 + dc] = *(const uint4*)(Qg + goff);
            *(uint4*)&Ks[l * 72 + dc] = *(const uint4*)(Kg + goff);
            *(uint4*)&Vt[l * 72 + dc] =
                *(const uint4*)(Vg + (size_t)n * 131072 + (size_t)l * 2048 + c * 64 + dc);
        }
        __syncthreads();

        short8 qfv[2];
        #pragma unroll
        for (int kh = 0; kh < 2; ++kh)
            qfv[kh] = *(const short8*)&Qs[(w * 16 + fr) * 72 + kh * 32 + q * 8];

        f32x4 oacc[4];
        #pragma unroll
        for (int mt = 0; mt < 4; ++mt) oacc[mt] = zero4;

        // O = Q @ Sprev^T (Sps in LDS)
        #pragma unroll
        for (int mt = 0; mt < 4; ++mt) {
            #pragma unroll
            for (int kh = 0; kh < 2; ++kh) {
                short8 sf = *(const short8*)&Sps[(mt * 16 + fr) * 72 + kh * 32 + q * 8];
                oacc[mt] = __builtin_amdgcn_mfma_f32_16x16x32_bf16(qfv[kh], sf, oacc[mt], 0, 0, 0);
            }
        }

        unsigned short* myPs = &Ps[w * 640];      // 16 x 40
        int rbase = q * 4;
        int njt = (w >> 1) + 1;                   // 32-wide j-tiles for this wave
        for (int jt = 0; jt < njt; ++jt) {        // wave-uniform; barrier-free
            f32x4 pacc[2];
            pacc[0] = zero4; pacc[1] = zero4;
            #pragma unroll
            for (int jt16 = 0; jt16 < 2; ++jt16) {
                #pragma unroll
                for (int kh = 0; kh < 2; ++kh) {
                    short8 kf = *(const short8*)&Ks[(jt * 32 + jt16 * 16 + fr) * 72 + kh * 32 + q * 8];
                    pacc[jt16] = __builtin_amdgcn_mfma_f32_16x16x32_bf16(qfv[kh], kf, pacc[jt16], 0, 0, 0);
                }
            }
            bool diag = (jt == njt - 1);
            int lloc = w * 16 + rbase;
            #pragma unroll
            for (int jt16 = 0; jt16 < 2; ++jt16)
                #pragma unroll
                for (int r = 0; r < 4; ++r) {
                    int jl = jt * 32 + jt16 * 16 + fr;
                    float pv = pacc[jt16][r];
                    if (diag && jl > lloc + r) pv = 0.f;
                    myPs[(rbase + r) * 40 + jt16 * 16 + fr] = f2bf(pv);
                }
            short8 pf = *(const short8*)&myPs[fr * 40 + q * 8];
            #pragma unroll
            for (int mt = 0; mt < 4; ++mt) {
                short8 vf = *(const short8*)&Vt[(mt * 16 + fr) * 72 + jt * 32 + q * 8];
                oacc[mt] = __builtin_amdgcn_mfma_f32_16x16x32_bf16(pf, vf, oacc[mt], 0, 0, 0);
            }
        }

        float rqv[4];
        #pragma unroll
        for (int r = 0; r < 4; ++r) {
            int flat = (c * 64 + w * 16 + rbase + r) * 2 + b;
            rqv[r] = 1.f / fmaxf(sqrtf(ssq[flat]), 1e-12f);
        }
        __syncthreads();                          // Qs dead -> O staging [l][m] stride 64
        #pragma unroll
        for (int mt = 0; mt < 4; ++mt)
            #pragma unroll
            for (int r = 0; r < 4; ++r)
                Qs[(w * 16 + rbase + r) * 64 + mt * 16 + fr] = f2bf(oacc[mt][r] * rqv[r]);
        __syncthreads();
        #pragma unroll
        for (int rep = 0; rep < 2; ++rep) {
            int idx8 = rep * 256 + tid;
            int l = idx8 >> 3, m8 = (idx8 & 7) * 8;
            *(uint4*)((unsigned short*)AOb + (size_t)((c * 64 + l) * 2 + b) * 512 + h * 64 + m8) =
                *(const uint4*)&Qs[l * 64 + m8];
        }
        __threadfence();
        __syncthreads();
        if (tid == 0) aadd(&flg[512 + c], 1);     // this head's chunk-c AOb rows are ready
    }

    // ---------- Phase D: output projection tile (remapped block ids) ----------
    {
        int x = blk & 63, y = blk >> 6;           // 64 x 8 tiles of 64x64
        int m0 = x * 64, n0 = y * 64;
        int cneed = x >> 1;                       // AOb rows [m0, m0+64) come from chunk x>>1
        if (tid == 0)
            while (aload(&flg[512 + cneed]) < 16) __builtin_amdgcn_s_sleep(1);
        __syncthreads();
        __threadfence();

        unsigned short* As = (unsigned short*)SMraw;            // 64x40
        unsigned short* Bs = (unsigned short*)(SMraw + 5120);   // [4][64][8]
        const unsigned short* Ag = (const unsigned short*)AOb;
        const unsigned short* Wg = (const unsigned short*)Wop;
        int wm = (w >> 1) * 32;
        int wn = (w & 1) * 32;
        int srow = tid >> 2;
        int skk  = (tid & 3) * 8;

        f32x4 acc[2][2];
        acc[0][0] = zero4; acc[0][1] = zero4; acc[1][0] = zero4; acc[1][1] = zero4;

        for (int kw = 0; kw < 16; ++kw) {
            int k0 = kw * 32, s0 = kw * 4;
            __syncthreads();
            *(uint4*)&As[srow * 40 + skk] = *(const uint4*)(Ag + (size_t)(m0 + srow) * 512 + k0 + skk);
            gl_lds16(Wg + ((size_t)(y * 64 + s0 + w) * 64 + lane) * 8, Bs + w * 512);
            __syncthreads();
            short8 af[2], bf[2];
            #pragma unroll
            for (int t = 0; t < 2; ++t) af[t] = *(const short8*)&As[(wm + t * 16 + fr) * 40 + q * 8];
            #pragma unroll
            for (int u = 0; u < 2; ++u) bf[u] = *(const short8*)&Bs[(q * 64 + wn + u * 16 + fr) * 8];
            #pragma unroll
            for (int t = 0; t < 2; ++t)
                #pragma unroll
                for (int u = 0; u < 2; ++u)
                    acc[t][u] = __builtin_amdgcn_mfma_f32_16x16x32_bf16(af[t], bf[u], acc[t][u], 0, 0, 0);
        }

        int rb = q * 4;
        float* Cf = (float*)SMraw;          // 64x64 fp32
        __syncthreads();
        #pragma unroll
        for (int t = 0; t < 2; ++t)
            #pragma unroll
            for (int u = 0; u < 2; ++u) {
                float bv = bo[n0 + wn + u * 16 + fr];
                #pragma unroll
                for (int r = 0; r < 4; ++r)
                    Cf[(wm + t * 16 + rb + r) * 64 + wn + u * 16 + fr] = acc[t][u][r] + bv;
            }
        __syncthreads();
        #pragma unroll
        for (int rep = 0; rep < 4; ++rep) {
            int idx = rep * 256 + tid;
            int row = idx >> 4, c4 = (idx & 15) * 4;
            *(float4*)(out + (size_t)(m0 + row) * 512 + n0 + c4) = *(const float4*)&Cf[row * 64 + c4];
        }
    }
}

// ---------------------------------------------------------------- launch
extern "C" void kernel_launch(void* const* d_in, const int* in_sizes, int n_in,
                              void* d_out, int out_size, void* d_ws, size_t ws_size,
                              hipStream_t stream)
{
    (void)in_sizes; (void)n_in; (void)out_size; (void)ws_size;
    const float* x  = (const float*)d_in[0];
    const float* Wq = (const float*)d_in[1];
    const float* bq = (const float*)d_in[2];
    const float* Wk = (const float*)d_in[3];
    const float* bk = (const float*)d_in[4];
    const float* Wv = (const float*)d_in[5];
    const float* bv = (const float*)d_in[6];
    const float* Wo = (const float*)d_in[7];
    const float* bo = (const float*)d_in[8];
    float* out = (float*)d_out;

    float* ssq = (float*)d_ws;            // 8192 f32
    int* flg = (int*)(ssq + 8192);        // 1024 int: [0..511] ScT flags, [512..543] done counters
    bf16* Xp  = (bf16*)(flg + 1024);      // packed 4096x512
    bf16* Wqp = Xp + 2097152;             // packed 512x512 each
    bf16* Wkp = Wqp + 262144;
    bf16* Wvp = Wkp + 262144;
    bf16* Wop = Wvp + 262144;
    bf16* Qb  = Wop + 262144;             // row-major bf16 q/k/v
    bf16* Kb  = Qb + 2097152;
    bf16* Vb  = Kb + 2097152;
    bf16* Vt  = Vb + 2097152;             // 16*64*2048
    bf16* AOb = Vt + 2097152;
    float* ScT = (float*)(AOb + 2097152); // 16*32*4096 f32

    pack_kernel<<<768, 256, 0, stream>>>(x, Wq, Wk, Wv, Wo, Xp, Wqp, Wkp, Wvp, Wop, ssq, flg);
    qkv_gemm_kernel<<<dim3(64, 4, 3), 256, 0, stream>>>(Xp, Wqp, Wkp, Wvp, bq, bk, bv, Qb, Kb, Vb, ssq);
    tail_kernel<<<512, 256, 0, stream>>>(Qb, Kb, Vb, Vt, AOb, ScT, ssq, flg, Wop, bo, out);
}

// Round 11
// 122.457 us; speedup vs baseline: 3.3567x; 3.3567x over previous
//
#include <hip/hip_runtime.h>
#include <hip/hip_bf16.h>

typedef __attribute__((ext_vector_type(8))) short short8;
typedef __attribute__((ext_vector_type(4))) float f32x4;
using bf16 = __hip_bfloat16;

__device__ __forceinline__ unsigned short f2bf(float f) {
    unsigned u = __float_as_uint(f);
    u += 0x7fff + ((u >> 16) & 1);           // round-to-nearest-even
    return (unsigned short)(u >> 16);
}
__device__ __forceinline__ float bf2f(unsigned short s) {
    return __uint_as_float(((unsigned)s) << 16);
}
// async global->LDS DMA, 16B/lane; global lane addrs CONTIGUOUS (packed layout)
__device__ __forceinline__ void gl_lds16(const unsigned short* g, unsigned short* l) {
    __builtin_amdgcn_global_load_lds(
        (const __attribute__((address_space(1))) unsigned int*)g,
        (__attribute__((address_space(3))) unsigned int*)l, 16, 0, 0);
}

// Packed layout (shorts): off = ((g*64 + s)*64 + r)*8   g=row/64, s=k/8, r=row%64
// => a wave staging (g, s, rows 0..63) reads 64 lanes x 16B = 1KB contiguous.

// ---------------------------------------------------------------- pack fp32 -> packed bf16 (+ zero ssq)
__global__ __launch_bounds__(256) void pack_kernel(
    const float* __restrict__ X, const float* __restrict__ Wq, const float* __restrict__ Wk,
    const float* __restrict__ Wv, const float* __restrict__ Wo,
    bf16* __restrict__ Xp, bf16* __restrict__ Wqp, bf16* __restrict__ Wkp,
    bf16* __restrict__ Wvp, bf16* __restrict__ Wop, float* __restrict__ ssq)
{
    __shared__ __align__(16) unsigned short sm[4096];   // [s_local 8][r 64][8]
    int id = blockIdx.x;
    int tid = threadIdx.x;
    if (id < 8) {
        int zi = id * 1024 + tid * 4;
        *(float4*)&ssq[zi] = make_float4(0.f, 0.f, 0.f, 0.f);
    }
    const float* src; unsigned short* dst; int g, sc;
    if (id < 512) { src = X; dst = (unsigned short*)Xp; g = id >> 3; sc = id & 7; }
    else {
        int t = id - 512; int wsel = t >> 6; int u = t & 63;
        g = u >> 3; sc = u & 7;
        src = (wsel == 0) ? Wq : ((wsel == 1) ? Wk : ((wsel == 2) ? Wv : Wo));
        dst = (unsigned short*)((wsel == 0) ? Wqp : ((wsel == 1) ? Wkp : ((wsel == 2) ? Wvp : Wop)));
    }
    int r = tid >> 2, kq = tid & 3;          // 64 rows x 4 k-chunks of 16
    const float* sp = src + (size_t)(g * 64 + r) * 512 + sc * 64 + kq * 16;
    #pragma unroll
    for (int i = 0; i < 4; ++i) {
        float4 v = *(const float4*)(sp + i * 4);
        int kk = kq * 16 + i * 4;            // local k 0..63
        int sl = kk >> 3, el = kk & 7;       // el in {0,4}
        ushort4 u4;
        u4.x = f2bf(v.x); u4.y = f2bf(v.y); u4.z = f2bf(v.z); u4.w = f2bf(v.w);
        *(ushort4*)&sm[(sl * 64 + r) * 8 + el] = u4;
    }
    __syncthreads();
    unsigned short* dp = dst + (size_t)g * 32768 + sc * 4096;   // 8 s-values contiguous
    *(uint4*)(dp + tid * 16)     = *(const uint4*)&sm[tid * 16];
    *(uint4*)(dp + tid * 16 + 8) = *(const uint4*)&sm[tid * 16 + 8];
}

// ---------------------------------------------------------------- QKV GEMM (packed bf16 in, bf16 out + sumsq)
// Out(z) = act(x @ W(z)^T + b(z)) bf16; z<2 accumulates per-row sumsq (post-relu) into ssq[z*4096+row].
// Tile 64x128; staging = pure global_load_lds_dwordx4 (3/wave/k-iter).  Grid (64,4,3) = 768 blocks.
__global__ __launch_bounds__(256) void qkv_gemm_kernel(
    const bf16* __restrict__ Xp,
    const bf16* __restrict__ W0p, const bf16* __restrict__ W1p, const bf16* __restrict__ W2p,
    const float* __restrict__ b0, const float* __restrict__ b1, const float* __restrict__ b2,
    bf16* __restrict__ O0, bf16* __restrict__ O1, bf16* __restrict__ O2,
    float* __restrict__ ssq)
{
    __shared__ __align__(16) unsigned short smem[8192];   // As[4][64][8] 2048 + Bs[4][128][8] 4096; epilogue C 64x128
    unsigned short* As = smem;
    unsigned short* Bs = smem + 2048;
    int z = blockIdx.z;
    const unsigned short* Wg = (const unsigned short*)((z == 0) ? W0p : ((z == 1) ? W1p : W2p));
    const float* bias = (z == 0) ? b0 : ((z == 1) ? b1 : b2);
    unsigned short* Out = (unsigned short*)((z == 0) ? O0 : ((z == 1) ? O1 : O2));
    const unsigned short* Ag = (const unsigned short*)Xp;

    int g  = blockIdx.x;              // m-group (64 rows)
    int gB = blockIdx.y * 2;          // two 64-row W groups = 128 n
    int m0 = g * 64;
    int n0 = blockIdx.y * 128;
    int tid = threadIdx.x;
    int lane = tid & 63;
    int w = tid >> 6;
    int wm = (w >> 1) * 32;
    int wn = (w & 1) * 64;
    int fr = lane & 15, qf = lane >> 4;

    f32x4 zero4 = {0.f, 0.f, 0.f, 0.f};
    f32x4 acc[2][4];
    #pragma unroll
    for (int t = 0; t < 2; ++t)
        #pragma unroll
        for (int u = 0; u < 4; ++u) acc[t][u] = zero4;

    for (int kw = 0; kw < 16; ++kw) {
        int s0 = kw * 4;
        __syncthreads();
        gl_lds16(Ag + ((size_t)(g * 64 + s0 + w) * 64 + lane) * 8, As + w * 512);
        gl_lds16(Wg + ((size_t)(gB * 64 + s0 + w) * 64 + lane) * 8, Bs + w * 1024);
        gl_lds16(Wg + ((size_t)((gB + 1) * 64 + s0 + w) * 64 + lane) * 8, Bs + w * 1024 + 512);
        __syncthreads();
        short8 af[2], bfr[4];
        #pragma unroll
        for (int t = 0; t < 2; ++t) af[t] = *(const short8*)&As[(qf * 64 + wm + t * 16 + fr) * 8];
        #pragma unroll
        for (int u = 0; u < 4; ++u) bfr[u] = *(const short8*)&Bs[(qf * 128 + wn + u * 16 + fr) * 8];
        #pragma unroll
        for (int t = 0; t < 2; ++t)
            #pragma unroll
            for (int u = 0; u < 4; ++u)
                acc[t][u] = __builtin_amdgcn_mfma_f32_16x16x32_bf16(af[t], bfr[u], acc[t][u], 0, 0, 0);
    }

    bool relu = (z < 2);
    int rb = qf * 4;
    #pragma unroll
    for (int t = 0; t < 2; ++t)
        #pragma unroll
        for (int u = 0; u < 4; ++u) {
            float bv = bias[n0 + wn + u * 16 + fr];
            #pragma unroll
            for (int r = 0; r < 4; ++r) {
                float v = acc[t][u][r] + bv;
                if (relu) v = fmaxf(v, 0.f);
                acc[t][u][r] = v;
            }
        }
    if (relu) {
        #pragma unroll
        for (int t = 0; t < 2; ++t)
            #pragma unroll
            for (int r = 0; r < 4; ++r) {
                float s = 0.f;
                #pragma unroll
                for (int u = 0; u < 4; ++u) s += acc[t][u][r] * acc[t][u][r];
                #pragma unroll
                for (int off = 1; off < 16; off <<= 1) s += __shfl_xor(s, off, 64);
                if (fr == 0) atomicAdd(&ssq[z * 4096 + m0 + wm + t * 16 + rb + r], s);
            }
    }
    __syncthreads();                       // LDS dead -> C staging [row][128]
    #pragma unroll
    for (int t = 0; t < 2; ++t)
        #pragma unroll
        for (int u = 0; u < 4; ++u)
            #pragma unroll
            for (int r = 0; r < 4; ++r)
                smem[(wm + t * 16 + rb + r) * 128 + wn + u * 16 + fr] = f2bf(acc[t][u][r]);
    __syncthreads();
    #pragma unroll
    for (int rep = 0; rep < 4; ++rep) {
        int idx8 = rep * 256 + tid;
        int row = idx8 >> 4, col8 = (idx8 & 15) * 8;
        *(uint4*)(Out + (size_t)(m0 + row) * 512 + n0 + col8) = *(const uint4*)&smem[row * 128 + col8];
    }
}

// ---------------------------------------------------------------- per-chunk (64 rows) KV sums + scaled V^T
// ScT[(n*32+c)*4096 + m*64 + d] = sum_{j in 64-chunk c} k[j][d]*v'[j][m], v' = v/|k_row|
// Vt_g[n][m][l] = v'[l][m] bf16.   Grid 512 = (n 16, c 32) -> 2 blocks/CU.
__global__ __launch_bounds__(256) void chunk_kv_kernel(
    const bf16* __restrict__ Kb, const bf16* __restrict__ Vb,
    const float* __restrict__ ssq, float* __restrict__ ScT, bf16* __restrict__ Vt_g)
{
    int n = blockIdx.x >> 5, c = blockIdx.x & 31;
    int b = n >> 3, h = n & 7;
    __shared__ float Ks[64 * 64];
    __shared__ float Vs[64 * 64];
    const unsigned short* Kg = (const unsigned short*)Kb;
    const unsigned short* Vg = (const unsigned short*)Vb;
    int tid = threadIdx.x;
    int td = tid >> 4, tm = tid & 15;
    int d0 = td * 4, m0 = tm * 4;
    #pragma unroll
    for (int rep = 0; rep < 4; ++rep) {
        int idx = rep * 1024 + tid * 4;
        int j = idx >> 6, d = idx & 63;
        int grow = (c * 64 + j) * 2 + b;
        ushort4 ku = *(const ushort4*)&Kg[(size_t)grow * 512 + h * 64 + d];
        ushort4 vu = *(const ushort4*)&Vg[(size_t)grow * 512 + h * 64 + d];
        float rk = 1.f / fmaxf(sqrtf(ssq[4096 + grow]), 1e-12f);
        *(float4*)&Ks[j * 64 + d] = make_float4(bf2f(ku.x), bf2f(ku.y), bf2f(ku.z), bf2f(ku.w));
        *(float4*)&Vs[j * 64 + d] = make_float4(bf2f(vu.x) * rk, bf2f(vu.y) * rk,
                                                bf2f(vu.z) * rk, bf2f(vu.w) * rk);
    }
    __syncthreads();
    float acc[4][4] = {};
    for (int j = 0; j < 64; ++j) {
        float4 kv = *(const float4*)&Ks[j * 64 + d0];
        float4 vv = *(const float4*)&Vs[j * 64 + m0];
        acc[0][0] += kv.x*vv.x; acc[0][1] += kv.x*vv.y; acc[0][2] += kv.x*vv.z; acc[0][3] += kv.x*vv.w;
        acc[1][0] += kv.y*vv.x; acc[1][1] += kv.y*vv.y; acc[1][2] += kv.y*vv.z; acc[1][3] += kv.y*vv.w;
        acc[2][0] += kv.z*vv.x; acc[2][1] += kv.z*vv.y; acc[2][2] += kv.z*vv.z; acc[2][3] += kv.z*vv.w;
        acc[3][0] += kv.w*vv.x; acc[3][1] += kv.w*vv.y; acc[3][2] += kv.w*vv.z; acc[3][3] += kv.w*vv.w;
    }
    // scaled V^T bf16: thread -> m = tid&63, 16 j's starting at (tid>>6)*16
    int vm = tid & 63, vj0 = (tid >> 6) * 16;
    unsigned short tmp[16];
    #pragma unroll
    for (int i = 0; i < 16; ++i) tmp[i] = f2bf(Vs[(vj0 + i) * 64 + vm]);
    size_t vtoff = (size_t)n * 131072 + (size_t)vm * 2048 + c * 64 + vj0;
    *(uint4*)((unsigned short*)Vt_g + vtoff)     = *(uint4*)&tmp[0];
    *(uint4*)((unsigned short*)Vt_g + vtoff + 8) = *(uint4*)&tmp[8];

    float* outp = ScT + (size_t)blockIdx.x * 4096;
    #pragma unroll
    for (int j2 = 0; j2 < 4; ++j2) {
        float4 o4 = make_float4(acc[0][j2], acc[1][j2], acc[2][j2], acc[3][j2]);
        *(float4*)&outp[(m0 + j2) * 64 + d0] = o4;
    }
}

// ---------------------------------------------------------------- exclusive chunk prefix (32 planes) -> SpT bf16
__global__ __launch_bounds__(256) void prefix_kernel(const float* __restrict__ ScT, bf16* __restrict__ SpT)
{
    int n = blockIdx.x >> 4;
    int idx = ((blockIdx.x & 15) << 8) + threadIdx.x;   // 0..4095 within plane
    size_t base = (size_t)n * 131072 + idx;
    unsigned short* sp = (unsigned short*)SpT;
    float run = 0.f;
    #pragma unroll
    for (int c = 0; c < 32; ++c) {
        size_t off = base + (size_t)c * 4096;
        sp[off] = f2bf(run);
        run += ScT[off];
    }
}

// ---------------------------------------------------------------- MFMA causal linear attention per (head, 64-chunk)
// out[l] = (1/|q_l|) * [ q_l @ Sprev + sum_{j<=l in chunk} (q_l . k_j) v'_j ].  Grid 512 -> 2 blocks/CU.
__global__ __launch_bounds__(256) void attn_kernel(
    const bf16* __restrict__ Qb, const bf16* __restrict__ Kb,
    const bf16* __restrict__ Vt_g, const bf16* __restrict__ SpT_g,
    const float* __restrict__ ssq, bf16* __restrict__ AOb)
{
    int n = blockIdx.x >> 5, c = blockIdx.x & 31;
    int b = n >> 3, h = n & 7;
    __shared__ unsigned short Qs[64 * 72];   // [l][d]
    __shared__ unsigned short Ks[64 * 72];   // [j][d]
    __shared__ unsigned short Vt[64 * 72];   // [m][j]
    __shared__ unsigned short Ps[4 * 16 * 40];
    int tid = threadIdx.x;
    int lane = tid & 63;
    int w = tid >> 6;
    int fr = lane & 15, q = lane >> 4;

    const unsigned short* Qg = (const unsigned short*)Qb;
    const unsigned short* Kg = (const unsigned short*)Kb;
    const unsigned short* Vg = (const unsigned short*)Vt_g;

    #pragma unroll
    for (int rep = 0; rep < 2; ++rep) {
        int idx = rep * 256 + tid;
        int l = idx >> 3, dc = (idx & 7) * 8;
        size_t goff = (size_t)((c * 64 + l) * 2 + b) * 512 + h * 64 + dc;
        *(uint4*)&Qs[l * 72 + dc] = *(const uint4*)(Qg + goff);
        *(uint4*)&Ks[l * 72 + dc] = *(const uint4*)(Kg + goff);
        int m = l, jc = dc;
        *(uint4*)&Vt[m * 72 + jc] =
            *(const uint4*)(Vg + (size_t)n * 131072 + (size_t)m * 2048 + c * 64 + jc);
    }
    __syncthreads();

    short8 qf[2];
    #pragma unroll
    for (int kh = 0; kh < 2; ++kh)
        qf[kh] = *(const short8*)&Qs[(w * 16 + fr) * 72 + kh * 32 + q * 8];

    f32x4 zero4 = {0.f, 0.f, 0.f, 0.f};
    f32x4 oacc[4];
    #pragma unroll
    for (int mt = 0; mt < 4; ++mt) oacc[mt] = zero4;

    // O = Q @ Sprev^T (one 64x64 bf16 plane, L2-hot)
    const unsigned short* spg = (const unsigned short*)SpT_g + (size_t)blockIdx.x * 4096;
    #pragma unroll
    for (int mt = 0; mt < 4; ++mt) {
        #pragma unroll
        for (int kh = 0; kh < 2; ++kh) {
            short8 sf = *(const short8*)&spg[(mt * 16 + fr) * 64 + kh * 32 + q * 8];
            oacc[mt] = __builtin_amdgcn_mfma_f32_16x16x32_bf16(qf[kh], sf, oacc[mt], 0, 0, 0);
        }
    }

    unsigned short* myPs = &Ps[w * 640];      // 16 x 40
    int rbase = q * 4;
    int njt = (w >> 1) + 1;                   // 32-wide j-tiles needed by this wave
    for (int jt = 0; jt < njt; ++jt) {        // wave-uniform; barrier-free
        f32x4 pacc[2];
        pacc[0] = zero4; pacc[1] = zero4;
        #pragma unroll
        for (int jt16 = 0; jt16 < 2; ++jt16) {
            #pragma unroll
            for (int kh = 0; kh < 2; ++kh) {
                short8 kf = *(const short8*)&Ks[(jt * 32 + jt16 * 16 + fr) * 72 + kh * 32 + q * 8];
                pacc[jt16] = __builtin_amdgcn_mfma_f32_16x16x32_bf16(qf[kh], kf, pacc[jt16], 0, 0, 0);
            }
        }
        bool diag = (jt == njt - 1);
        int lloc = w * 16 + rbase;            // + r
        #pragma unroll
        for (int jt16 = 0; jt16 < 2; ++jt16)
            #pragma unroll
            for (int r = 0; r < 4; ++r) {
                int jl = jt * 32 + jt16 * 16 + fr;
                float pv = pacc[jt16][r];
                if (diag && jl > lloc + r) pv = 0.f;
                myPs[(rbase + r) * 40 + jt16 * 16 + fr] = f2bf(pv);
            }
        short8 pf = *(const short8*)&myPs[fr * 40 + q * 8];
        #pragma unroll
        for (int mt = 0; mt < 4; ++mt) {
            short8 vf = *(const short8*)&Vt[(mt * 16 + fr) * 72 + jt * 32 + q * 8];
            oacc[mt] = __builtin_amdgcn_mfma_f32_16x16x32_bf16(pf, vf, oacc[mt], 0, 0, 0);
        }
    }

    // scale rows by 1/|q_l|, stage, coalesced store
    float rqv[4];
    #pragma unroll
    for (int r = 0; r < 4; ++r) {
        int flat = (c * 64 + w * 16 + rbase + r) * 2 + b;
        rqv[r] = 1.f / fmaxf(sqrtf(ssq[flat]), 1e-12f);
    }
    __syncthreads();                          // Qs dead -> O staging [l][m] stride 64
    #pragma unroll
    for (int mt = 0; mt < 4; ++mt)
        #pragma unroll
        for (int r = 0; r < 4; ++r)
            Qs[(w * 16 + rbase + r) * 64 + mt * 16 + fr] = f2bf(oacc[mt][r] * rqv[r]);
    __syncthreads();
    #pragma unroll
    for (int rep = 0; rep < 2; ++rep) {
        int idx8 = rep * 256 + tid;
        int l = idx8 >> 3, m8 = (idx8 & 7) * 8;
        *(uint4*)((unsigned short*)AOb + (size_t)((c * 64 + l) * 2 + b) * 512 + h * 64 + m8) =
            *(const uint4*)&Qs[l * 64 + m8];
    }
}

// ---------------------------------------------------------------- output projection: 64x64 tile, grid (64,8)=512
__global__ __launch_bounds__(256) void oproj_kernel(
    const bf16* __restrict__ A, const bf16* __restrict__ Wop,
    const float* __restrict__ bias, float* __restrict__ Out)
{
    __shared__ __align__(16) unsigned short smem[8192];  // As 64x40 (2560) + Bs[4][64][8] (2048); epilogue C 64x64 f32
    unsigned short* As = smem;
    unsigned short* Bs = smem + 2560;
    const unsigned short* Ag = (const unsigned short*)A;
    const unsigned short* Wg = (const unsigned short*)Wop;
    int m0 = blockIdx.x * 64;
    int gy = blockIdx.y;
    int n0 = gy * 64;
    int tid = threadIdx.x;
    int lane = tid & 63;
    int w = tid >> 6;
    int fr = lane & 15, qf = lane >> 4;
    int wm = (w >> 1) * 32;
    int wn = (w & 1) * 32;
    int srow = tid >> 2;
    int skk  = (tid & 3) * 8;

    f32x4 zero4 = {0.f, 0.f, 0.f, 0.f};
    f32x4 acc[2][2];
    acc[0][0] = zero4; acc[0][1] = zero4; acc[1][0] = zero4; acc[1][1] = zero4;

    for (int kw = 0; kw < 16; ++kw) {
        int k0 = kw * 32, s0 = kw * 4;
        __syncthreads();
        *(uint4*)&As[srow * 40 + skk] = *(const uint4*)(Ag + (size_t)(m0 + srow) * 512 + k0 + skk);
        gl_lds16(Wg + ((size_t)(gy * 64 + s0 + w) * 64 + lane) * 8, Bs + w * 512);
        __syncthreads();
        short8 af[2], bf[2];
        #pragma unroll
        for (int t = 0; t < 2; ++t) af[t] = *(const short8*)&As[(wm + t * 16 + fr) * 40 + qf * 8];
        #pragma unroll
        for (int u = 0; u < 2; ++u) bf[u] = *(const short8*)&Bs[(qf * 64 + wn + u * 16 + fr) * 8];
        #pragma unroll
        for (int t = 0; t < 2; ++t)
            #pragma unroll
            for (int u = 0; u < 2; ++u)
                acc[t][u] = __builtin_amdgcn_mfma_f32_16x16x32_bf16(af[t], bf[u], acc[t][u], 0, 0, 0);
    }

    int rb = qf * 4;
    float* Cf = (float*)smem;          // 64 x 64 fp32
    __syncthreads();
    #pragma unroll
    for (int t = 0; t < 2; ++t)
        #pragma unroll
        for (int u = 0; u < 2; ++u) {
            float bv = bias[n0 + wn + u * 16 + fr];
            #pragma unroll
            for (int r = 0; r < 4; ++r)
                Cf[(wm + t * 16 + rb + r) * 64 + wn + u * 16 + fr] = acc[t][u][r] + bv;
        }
    __syncthreads();
    #pragma unroll
    for (int rep = 0; rep < 4; ++rep) {
        int idx = rep * 256 + tid;
        int row = idx >> 4, c4 = (idx & 15) * 4;
        *(float4*)(Out + (size_t)(m0 + row) * 512 + n0 + c4) = *(const float4*)&Cf[row * 64 + c4];
    }
}

// ---------------------------------------------------------------- launch
extern "C" void kernel_launch(void* const* d_in, const int* in_sizes, int n_in,
                              void* d_out, int out_size, void* d_ws, size_t ws_size,
                              hipStream_t stream)
{
    (void)in_sizes; (void)n_in; (void)out_size; (void)ws_size;
    const float* x  = (const float*)d_in[0];
    const float* Wq = (const float*)d_in[1];
    const float* bq = (const float*)d_in[2];
    const float* Wk = (const float*)d_in[3];
    const float* bk = (const float*)d_in[4];
    const float* Wv = (const float*)d_in[5];
    const float* bv = (const float*)d_in[6];
    const float* Wo = (const float*)d_in[7];
    const float* bo = (const float*)d_in[8];
    float* out = (float*)d_out;

    float* ssq = (float*)d_ws;            // 8192 f32
    bf16* Xp  = (bf16*)(ssq + 8192);      // packed 4096x512
    bf16* Wqp = Xp + 2097152;             // packed 512x512 each
    bf16* Wkp = Wqp + 262144;
    bf16* Wvp = Wkp + 262144;
    bf16* Wop = Wvp + 262144;
    bf16* Qb  = Wop + 262144;             // row-major bf16 q/k/v
    bf16* Kb  = Qb + 2097152;
    bf16* Vb  = Kb + 2097152;
    bf16* Vt  = Vb + 2097152;             // 16*64*2048
    bf16* AOb = Vt + 2097152;
    bf16* SpT = AOb + 2097152;            // 16*32*4096 bf16
    float* ScT = (float*)(SpT + 2097152); // 16*32*4096 f32

    pack_kernel<<<768, 256, 0, stream>>>(x, Wq, Wk, Wv, Wo, Xp, Wqp, Wkp, Wvp, Wop, ssq);
    qkv_gemm_kernel<<<dim3(64, 4, 3), 256, 0, stream>>>(Xp, Wqp, Wkp, Wvp, bq, bk, bv, Qb, Kb, Vb, ssq);
    chunk_kv_kernel<<<dim3(512), 256, 0, stream>>>(Kb, Vb, ssq, ScT, Vt);
    prefix_kernel<<<dim3(256), 256, 0, stream>>>(ScT, SpT);
    attn_kernel<<<dim3(512), 256, 0, stream>>>(Qb, Kb, Vt, SpT, ssq, AOb);
    oproj_kernel<<<dim3(64, 8), 256, 0, stream>>>(AOb, Wop, bo, out);
}